// Round 1
// baseline (989.335 us; speedup 1.0000x reference)
//
#include <hip/hip_runtime.h>
#include <hip/hip_bf16.h>
#include <cstdint>

typedef __attribute__((ext_vector_type(8))) short bf16x8;
typedef __attribute__((ext_vector_type(4))) float f32x4;

#define NTOK 49
#define CDIM 256
#define NHEAD 8
#define SCALE 0.17677669529663687f

// ---- workspace layout (bytes) ----
#define WTQ_OFF  0                      // 196608 ushort (bf16)  W^T [768][256]
#define WTP_OFF  (196608 * 2)           // 65536 ushort (bf16)   proj^T [256][256]
#define BIAS_OFF (WTP_OFF + 65536 * 2)  // 19208 float           bias[h][49][49]

// ---- LDS layout (bytes) ----
#define QK_OFF   0                        // [50][512] bf16, stride 1024 (q cols 0..255, k cols 256..511)
#define VT_OFF   51200                    // [256][64] bf16, stride 128  (vT[d][n])
#define P_OFF    (51200 + 32768)          // 8 * [32][64] bf16 (4096 B per wave)
#define XS_OFF   (P_OFF + 32768)          // [50][256] bf16, stride 512 (x staged; reused as attn_out)
#define MB_OFF   (XS_OFF + 25600)         // 76+ dwords mask bits
#define LDS_TOTAL (MB_OFF + 320)          // 142656 B

__device__ __forceinline__ ushort f2bf(float f) {
  uint u = __builtin_bit_cast(uint, f);
  u += 0x7fffu + ((u >> 16) & 1u);
  return (ushort)(u >> 16);
}

extern "C" __global__ void wattn_prep(const float* __restrict__ qkv_w,
                                      const float* __restrict__ proj_w,
                                      const float* __restrict__ bt,
                                      ushort* __restrict__ WTq,
                                      ushort* __restrict__ WTp,
                                      float* __restrict__ biasH) {
  int id = blockIdx.x * 256 + threadIdx.x;  // grid covers 196608
  if (id < 196608) {
    int n = id >> 8, k = id & 255;
    WTq[id] = f2bf(qkv_w[k * 768 + n]);     // W^T[n][k] = W[k][n]
  }
  if (id < 65536) {
    int oc = id >> 8, ic = id & 255;
    WTp[id] = f2bf(proj_w[ic * 256 + oc]);  // proj^T[oc][ic]
  }
  if (id < 19208) {
    int h = id / 2401, r2 = id % 2401;
    int n = r2 / 49, m = r2 % 49;
    int dx = (n % 7) - (m % 7);
    int dy = (n / 7) - (m / 7);
    int idx = 13 * (dx + dy + 12);          // reference formula (both coords *13, summed)
    if (idx > 168) idx = 168;               // JAX clamps OOB gather
    biasH[id] = bt[idx * 8 + h];
  }
}

extern "C" __global__ __launch_bounds__(512)
void wattn_fused(const float* __restrict__ x, const int* __restrict__ mask,
                 const float* __restrict__ qkv_b, const float* __restrict__ proj_b,
                 const ushort* __restrict__ WTq, const ushort* __restrict__ WTp,
                 const float* __restrict__ biasH, float* __restrict__ out) {
  extern __shared__ char lds[];
  const int tid  = threadIdx.x;
  const int wid  = tid >> 6;   // wave id == head id
  const int lane = tid & 63;
  const int g    = lane >> 4;  // 4 lane-groups
  const int c    = lane & 15;
  const int b    = blockIdx.x;

  // ---------------- Phase 0: stage x -> xs (bf16, swizzled) + mask bitmask ----------------
  {
    const float4* xb = (const float4*)(x + (size_t)b * (NTOK * CDIM));
    #pragma unroll 2
    for (int i = tid; i < (NTOK * CDIM / 4); i += 512) {
      float4 v = xb[i];
      int r = i >> 6;               // row 0..48
      int cc = (i & 63) << 2;       // col
      uint off = (uint)(XS_OFF + r * 512 + cc * 2) ^ ((uint)(r & 7) << 4);
      ushort4 h4;
      h4.x = f2bf(v.x); h4.y = f2bf(v.y); h4.z = f2bf(v.z); h4.w = f2bf(v.w);
      *(ushort4*)(lds + off) = h4;
    }
    if (tid < 64) {  // zero pad row 49
      uint off = (uint)(XS_OFF + 49 * 512 + tid * 8) ^ ((uint)(49 & 7) << 4);
      ushort4 z; z.x = 0; z.y = 0; z.z = 0; z.w = 0;
      *(ushort4*)(lds + off) = z;
    }
    const int* mw = mask + (size_t)(b & 1023) * (NTOK * NTOK);
    for (int i = tid; i < 76; i += 512) {
      uint word = 0;
      int base = i * 32;
      int lim = NTOK * NTOK - base; if (lim > 32) lim = 32;
      for (int j = 0; j < lim; ++j) word |= (mw[base + j] ? 1u : 0u) << j;
      ((uint*)(lds + MB_OFF))[i] = word;
    }
  }
  __syncthreads();

  const f32x4 zero4 = {0.f, 0.f, 0.f, 0.f};

  // ---------------- Phase 1: QKV GEMM for head `wid` ----------------
  {
    const int h = wid;
    f32x4 acc[4][6];
    #pragma unroll
    for (int rt = 0; rt < 4; ++rt)
      #pragma unroll
      for (int nt = 0; nt < 6; ++nt) acc[rt][nt] = zero4;

    int colbase[6];
    #pragma unroll
    for (int nt = 0; nt < 6; ++nt) colbase[nt] = (nt >> 1) * 256 + h * 32 + (nt & 1) * 16;

    for (int ks = 0; ks < 8; ++ks) {
      bf16x8 a[4];
      #pragma unroll
      for (int rt = 0; rt < 4; ++rt) {
        int row = rt * 16 + c; if (row > 49) row = 49;
        uint off = (uint)(XS_OFF + row * 512 + (ks * 32 + g * 8) * 2) ^ ((uint)(row & 7) << 4);
        a[rt] = *(const bf16x8*)(lds + off);
      }
      #pragma unroll
      for (int nt = 0; nt < 6; ++nt) {
        const ushort* wp = WTq + (size_t)(colbase[nt] + c) * 256 + ks * 32 + g * 8;
        bf16x8 bf = *(const bf16x8*)wp;
        #pragma unroll
        for (int rt = 0; rt < 4; ++rt)
          acc[rt][nt] = __builtin_amdgcn_mfma_f32_16x16x32_bf16(a[rt], bf, acc[rt][nt], 0, 0, 0);
      }
    }
    // epilogue: +bias (q * scale), q/k -> QK region, v -> vT transposed
    #pragma unroll
    for (int nt = 0; nt < 6; ++nt) {
      float bv = qkv_b[colbase[nt] + c];
      #pragma unroll
      for (int rt = 0; rt < 4; ++rt) {
        f32x4 v = acc[rt][nt];
        if (nt < 4) {  // q or k
          int col = (nt < 2) ? (h * 32 + (nt & 1) * 16 + c)
                             : (256 + h * 32 + (nt & 1) * 16 + c);
          #pragma unroll
          for (int r = 0; r < 4; ++r) {
            int row = rt * 16 + g * 4 + r;
            if (row < 50) {
              float val = v[r] + bv;
              if (nt < 2) val *= SCALE;
              uint off = (uint)(QK_OFF + row * 1024 + col * 2) ^ ((uint)(row & 7) << 4);
              *(ushort*)(lds + off) = f2bf(val);
            }
          }
        } else {      // v -> vT[d][n]
          int d = h * 32 + (nt & 1) * 16 + c;
          ushort4 pk;
          pk.x = f2bf(v[0] + bv); pk.y = f2bf(v[1] + bv);
          pk.z = f2bf(v[2] + bv); pk.w = f2bf(v[3] + bv);
          int n0 = rt * 16 + g * 4;
          uint off = (uint)(VT_OFF + d * 128 + n0 * 2) ^ ((uint)(d & 7) << 4);
          *(ushort4*)(lds + off) = pk;
        }
      }
    }
  }
  __syncthreads();

  // ---------------- Phase 2: attention for head `wid`, two q-halves ----------------
  {
    const int h = wid;
    const uint pbase = (uint)(P_OFF + wid * 4096);
    #pragma unroll
    for (int hh = 0; hh < 2; ++hh) {
      const int qbase = hh * 32;
      // q A-frags
      bf16x8 aq[2];
      #pragma unroll
      for (int rt = 0; rt < 2; ++rt) {
        int row = qbase + rt * 16 + c; if (row > 49) row = 49;
        uint off = (uint)(QK_OFF + row * 1024 + (h * 32 + g * 8) * 2) ^ ((uint)(row & 7) << 4);
        aq[rt] = *(const bf16x8*)(lds + off);
      }
      // scores: S[q][key] over 4 key-tiles
      f32x4 s[2][4];
      #pragma unroll
      for (int kt = 0; kt < 4; ++kt) {
        int kr = kt * 16 + c; if (kr > 49) kr = 49;
        uint off = (uint)(QK_OFF + kr * 1024 + (256 + h * 32 + g * 8) * 2) ^ ((uint)(kr & 7) << 4);
        bf16x8 bk = *(const bf16x8*)(lds + off);
        #pragma unroll
        for (int rt = 0; rt < 2; ++rt)
          s[rt][kt] = __builtin_amdgcn_mfma_f32_16x16x32_bf16(aq[rt], bk, zero4, 0, 0, 0);
      }
      // + rel-pos bias + mask, pad cols/rows -> -1e30
      #pragma unroll
      for (int rt = 0; rt < 2; ++rt)
        #pragma unroll
        for (int kt = 0; kt < 4; ++kt) {
          int key = kt * 16 + c;
          #pragma unroll
          for (int r = 0; r < 4; ++r) {
            int q = qbase + rt * 16 + g * 4 + r;
            float sc = s[rt][kt][r];
            if (key > 48 || q > 48) {
              sc = -1e30f;
            } else {
              int bi = q * 49 + key;
              sc += biasH[h * 2401 + bi];
              sc -= 100.f * (float)((((const uint*)(lds + MB_OFF))[bi >> 5] >> (bi & 31)) & 1u);
            }
            s[rt][kt][r] = sc;
          }
        }
      // softmax (deferred normalization)
      float rdn[2][4];
      #pragma unroll
      for (int rt = 0; rt < 2; ++rt)
        #pragma unroll
        for (int r = 0; r < 4; ++r) {
          float m0 = fmaxf(fmaxf(s[rt][0][r], s[rt][1][r]), fmaxf(s[rt][2][r], s[rt][3][r]));
          m0 = fmaxf(m0, __shfl_xor(m0, 1));
          m0 = fmaxf(m0, __shfl_xor(m0, 2));
          m0 = fmaxf(m0, __shfl_xor(m0, 4));
          m0 = fmaxf(m0, __shfl_xor(m0, 8));
          float e0 = 0.f;
          #pragma unroll
          for (int kt = 0; kt < 4; ++kt) {
            float e = __expf(s[rt][kt][r] - m0);
            s[rt][kt][r] = e;
            e0 += e;
          }
          e0 += __shfl_xor(e0, 1);
          e0 += __shfl_xor(e0, 2);
          e0 += __shfl_xor(e0, 4);
          e0 += __shfl_xor(e0, 8);
          rdn[rt][r] = 1.0f / e0;
        }
      // write P (bf16, swizzled per-wave scratch)
      #pragma unroll
      for (int rt = 0; rt < 2; ++rt)
        #pragma unroll
        for (int kt = 0; kt < 4; ++kt)
          #pragma unroll
          for (int r = 0; r < 4; ++r) {
            int row = rt * 16 + g * 4 + r;
            uint off = (pbase + (uint)(row * 128 + (kt * 16 + c) * 2)) ^ ((uint)(row & 7) << 4);
            *(ushort*)(lds + off) = f2bf(s[rt][kt][r]);
          }
      // PV
      f32x4 o[2][2];
      #pragma unroll
      for (int rt = 0; rt < 2; ++rt)
        #pragma unroll
        for (int dt = 0; dt < 2; ++dt) o[rt][dt] = zero4;
      #pragma unroll
      for (int ks = 0; ks < 2; ++ks) {
        bf16x8 ap[2];
        #pragma unroll
        for (int rt = 0; rt < 2; ++rt) {
          int row = rt * 16 + c;
          uint off = (pbase + (uint)(row * 128 + (ks * 32 + g * 8) * 2)) ^ ((uint)(row & 7) << 4);
          ap[rt] = *(const bf16x8*)(lds + off);
        }
        #pragma unroll
        for (int dt = 0; dt < 2; ++dt) {
          int d = h * 32 + dt * 16 + c;
          uint off = (uint)(VT_OFF + d * 128 + (ks * 32 + g * 8) * 2) ^ ((uint)(d & 7) << 4);
          bf16x8 bv = *(const bf16x8*)(lds + off);
          #pragma unroll
          for (int rt = 0; rt < 2; ++rt)
            o[rt][dt] = __builtin_amdgcn_mfma_f32_16x16x32_bf16(ap[rt], bv, o[rt][dt], 0, 0, 0);
        }
      }
      // attn_out (bf16) into XS region
      #pragma unroll
      for (int rt = 0; rt < 2; ++rt)
        #pragma unroll
        for (int dt = 0; dt < 2; ++dt)
          #pragma unroll
          for (int r = 0; r < 4; ++r) {
            int q = qbase + rt * 16 + g * 4 + r;
            if (q < 50) {
              float val = o[rt][dt][r] * rdn[rt][r];
              int col = h * 32 + dt * 16 + c;
              uint off = (uint)(XS_OFF + q * 512 + col * 2) ^ ((uint)(q & 7) << 4);
              *(ushort*)(lds + off) = f2bf(val);
            }
          }
    }
  }
  __syncthreads();

  // ---------------- Phase 3: output projection ----------------
  {
    f32x4 po[4][2];
    #pragma unroll
    for (int rt = 0; rt < 4; ++rt) { po[rt][0] = zero4; po[rt][1] = zero4; }
    for (int ks = 0; ks < 8; ++ks) {
      bf16x8 ao[4];
      #pragma unroll
      for (int rt = 0; rt < 4; ++rt) {
        int row = rt * 16 + c; if (row > 49) row = 49;
        uint off = (uint)(XS_OFF + row * 512 + (ks * 32 + g * 8) * 2) ^ ((uint)(row & 7) << 4);
        ao[rt] = *(const bf16x8*)(lds + off);
      }
      #pragma unroll
      for (int ntl = 0; ntl < 2; ++ntl) {
        int oc = wid * 32 + ntl * 16 + c;
        const ushort* wp = WTp + (size_t)oc * 256 + ks * 32 + g * 8;
        bf16x8 bp = *(const bf16x8*)wp;
        #pragma unroll
        for (int rt = 0; rt < 4; ++rt)
          po[rt][ntl] = __builtin_amdgcn_mfma_f32_16x16x32_bf16(ao[rt], bp, po[rt][ntl], 0, 0, 0);
      }
    }
    float* ob = out + (size_t)b * (NTOK * CDIM);
    #pragma unroll
    for (int ntl = 0; ntl < 2; ++ntl) {
      int oc = wid * 32 + ntl * 16 + c;
      float bv = proj_b[oc];
      #pragma unroll
      for (int rt = 0; rt < 4; ++rt)
        #pragma unroll
        for (int r = 0; r < 4; ++r) {
          int q = rt * 16 + g * 4 + r;
          if (q < 49) ob[q * 256 + oc] = po[rt][ntl][r] + bv;
        }
    }
  }
}

extern "C" void kernel_launch(void* const* d_in, const int* in_sizes, int n_in,
                              void* d_out, int out_size, void* d_ws, size_t ws_size,
                              hipStream_t stream) {
  const float* x      = (const float*)d_in[0];
  const int*   mask   = (const int*)d_in[1];
  const float* qkv_w  = (const float*)d_in[2];
  const float* qkv_b  = (const float*)d_in[3];
  const float* proj_w = (const float*)d_in[4];
  const float* proj_b = (const float*)d_in[5];
  const float* bt     = (const float*)d_in[6];
  float* out = (float*)d_out;

  ushort* WTq  = (ushort*)d_ws;
  ushort* WTp  = (ushort*)((char*)d_ws + WTP_OFF);
  float*  biasH = (float*)((char*)d_ws + BIAS_OFF);

  hipLaunchKernelGGL(wattn_prep, dim3(768), dim3(256), 0, stream,
                     qkv_w, proj_w, bt, WTq, WTp, biasH);

  hipFuncSetAttribute(reinterpret_cast<const void*>(wattn_fused),
                      hipFuncAttributeMaxDynamicSharedMemorySize, LDS_TOTAL);
  hipLaunchKernelGGL(wattn_fused, dim3(8192), dim3(512), LDS_TOTAL, stream,
                     x, mask, qkv_b, proj_b, WTq, WTp, biasH, out);
}